// Round 1
// baseline (910.648 us; speedup 1.0000x reference)
//
#include <hip/hip_runtime.h>

#define N_NODES   100000
#define N_EDGES   1600000
#define N_FEAT    100
#define HIDDEN    64
#define N_CLASSES 47

// ---------------- degree / norm ----------------

__global__ void k_init_deg(float* __restrict__ deg) {
    int i = blockIdx.x * blockDim.x + threadIdx.x;
    if (i < N_NODES) deg[i] = 1.0f;   // self-loop contributes 1
}

__global__ void k_deg_edges(const int* __restrict__ col, float* __restrict__ deg) {
    int i = blockIdx.x * blockDim.x + threadIdx.x;
    if (i < N_EDGES) atomicAdd(&deg[col[i]], 1.0f);
}

__global__ void k_dinv(float* __restrict__ deg) {
    int i = blockIdx.x * blockDim.x + threadIdx.x;
    if (i < N_NODES) deg[i] = rsqrtf(deg[i]);   // deg >= 1 always
}

// ---------------- layer 0: xw = x@W0 ; h = dinv^2*xw + b0 ----------------
// block = 256 threads = 4 rows x 64 cols
__global__ __launch_bounds__(256) void k_gemm1(
    const float* __restrict__ x, const float* __restrict__ W0,
    const float* __restrict__ b0, const float* __restrict__ dinv,
    float* __restrict__ xw, float* __restrict__ h) {
    __shared__ float Ws[N_FEAT][HIDDEN];   // 25600 B
    __shared__ float Xs[4][N_FEAT];        // 1600 B
    int tid = threadIdx.x;
    for (int i = tid; i < N_FEAT * HIDDEN; i += 256)
        Ws[i / HIDDEN][i % HIDDEN] = W0[i];
    int row0 = blockIdx.x * 4;
    for (int i = tid; i < 4 * N_FEAT; i += 256) {
        int r = i / N_FEAT, k = i - r * N_FEAT;
        int row = row0 + r;
        Xs[r][k] = (row < N_NODES) ? x[row * N_FEAT + k] : 0.0f;
    }
    __syncthreads();
    int r = tid >> 6, c = tid & 63;
    int row = row0 + r;
    if (row < N_NODES) {
        float acc = 0.0f;
        #pragma unroll
        for (int k = 0; k < N_FEAT; ++k) acc += Xs[r][k] * Ws[k][c];
        xw[row * HIDDEN + c] = acc;
        float di = dinv[row];
        h[row * HIDDEN + c] = di * di * acc + b0[c];
    }
}

// ---------------- layer 0 scatter: h[col] += dinv[row]*dinv[col]*xw[row] ----
// one 64-lane wave per edge; lane = feature
__global__ __launch_bounds__(256) void k_scatter0(
    const int* __restrict__ erow, const int* __restrict__ ecol,
    const float* __restrict__ dinv, const float* __restrict__ xw,
    float* __restrict__ h) {
    unsigned t = blockIdx.x * 256u + threadIdx.x;
    int e = (int)(t >> 6);
    int f = (int)(t & 63u);
    if (e < N_EDGES) {
        int r = erow[e], c = ecol[e];
        float w = dinv[r] * dinv[c];
        atomicAdd(&h[c * HIDDEN + f], w * xw[r * HIDDEN + f]);
    }
}

// ---------------- layer 1: hw = relu(h)@W1 ; out = dinv^2*hw + b1 ----------
__global__ __launch_bounds__(256) void k_gemm2(
    const float* __restrict__ h, const float* __restrict__ W1,
    const float* __restrict__ b1, const float* __restrict__ dinv,
    float* __restrict__ hw, float* __restrict__ out) {
    __shared__ float Ws[HIDDEN][48];   // padded to 48, 12288 B
    __shared__ float Hs[4][HIDDEN];    // 1024 B
    int tid = threadIdx.x;
    for (int i = tid; i < HIDDEN * N_CLASSES; i += 256) {
        int k = i / N_CLASSES, c = i - k * N_CLASSES;
        Ws[k][c] = W1[i];
    }
    int row0 = blockIdx.x * 4;
    for (int i = tid; i < 4 * HIDDEN; i += 256) {
        int r = i >> 6, k = i & 63;
        int row = row0 + r;
        Hs[r][k] = (row < N_NODES) ? fmaxf(h[row * HIDDEN + k], 0.0f) : 0.0f;
    }
    __syncthreads();
    int r = tid >> 6, c = tid & 63;
    int row = row0 + r;
    if (row < N_NODES && c < N_CLASSES) {
        float acc = 0.0f;
        #pragma unroll
        for (int k = 0; k < HIDDEN; ++k) acc += Hs[r][k] * Ws[k][c];
        hw[row * N_CLASSES + c] = acc;
        float di = dinv[row];
        out[row * N_CLASSES + c] = di * di * acc + b1[c];
    }
}

// ---------------- layer 1 scatter: out[col] += norm * hw[row] --------------
__global__ __launch_bounds__(256) void k_scatter1(
    const int* __restrict__ erow, const int* __restrict__ ecol,
    const float* __restrict__ dinv, const float* __restrict__ hw,
    float* __restrict__ out) {
    unsigned t = blockIdx.x * 256u + threadIdx.x;
    int e = (int)(t >> 6);
    int f = (int)(t & 63u);
    if (e < N_EDGES && f < N_CLASSES) {
        int r = erow[e], c = ecol[e];
        float w = dinv[r] * dinv[c];
        atomicAdd(&out[c * N_CLASSES + f], w * hw[r * N_CLASSES + f]);
    }
}

extern "C" void kernel_launch(void* const* d_in, const int* in_sizes, int n_in,
                              void* d_out, int out_size, void* d_ws, size_t ws_size,
                              hipStream_t stream) {
    const float* x  = (const float*)d_in[0];
    const int*   ei = (const int*)d_in[1];
    const float* W0 = (const float*)d_in[2];
    const float* b0 = (const float*)d_in[3];
    const float* W1 = (const float*)d_in[4];
    const float* b1 = (const float*)d_in[5];
    float* out = (float*)d_out;

    char* ws = (char*)d_ws;
    float* dinv = (float*)(ws);                       // 400 KB
    float* xw   = (float*)(ws + (1u << 20));          // 25.6 MB
    float* h    = (float*)(ws + (1u << 20) + 26214400u); // 25.6 MB
    float* hw   = xw;                                  // reuse (18.8 MB <= 25.6 MB)

    const int* erow = ei;             // edge_index[0]
    const int* ecol = ei + N_EDGES;   // edge_index[1]

    k_init_deg<<<(N_NODES + 255) / 256, 256, 0, stream>>>(dinv);
    k_deg_edges<<<(N_EDGES + 255) / 256, 256, 0, stream>>>(ecol, dinv);
    k_dinv<<<(N_NODES + 255) / 256, 256, 0, stream>>>(dinv);

    k_gemm1<<<(N_NODES + 3) / 4, 256, 0, stream>>>(x, W0, b0, dinv, xw, h);
    k_scatter0<<<(N_EDGES * 64) / 256, 256, 0, stream>>>(erow, ecol, dinv, xw, h);

    k_gemm2<<<(N_NODES + 3) / 4, 256, 0, stream>>>(h, W1, b1, dinv, hw, out);
    k_scatter1<<<(N_EDGES * 64) / 256, 256, 0, stream>>>(erow, ecol, dinv, hw, out);
}

// Round 2
// 647.629 us; speedup vs baseline: 1.4061x; 1.4061x over previous
//
#include <hip/hip_runtime.h>

#define N_NODES   100000
#define N_EDGES   1600000
#define N_FEAT    100
#define HIDDEN    64
#define N_CLASSES 47
#define NODE_BLKS ((N_NODES + 255) / 256)   // 391
#define EDGE_BLKS ((N_EDGES + 255) / 256)   // 6250

// ---------------- CSR build: counting sort by destination ----------------

__global__ void k_zero(int* __restrict__ cnt) {
    int i = blockIdx.x * 256 + threadIdx.x;
    if (i < N_NODES) cnt[i] = 0;
}

__global__ void k_count(const int* __restrict__ ecol, int* __restrict__ cnt) {
    int e = blockIdx.x * 256 + threadIdx.x;
    if (e < N_EDGES) atomicAdd(&cnt[ecol[e]], 1);
}

// per-block exclusive scan; block totals to sums[]
__global__ __launch_bounds__(256) void k_scan1(const int* __restrict__ cnt,
                                               int* __restrict__ rp,
                                               int* __restrict__ sums) {
    __shared__ int tmp[256];
    int i = blockIdx.x * 256 + threadIdx.x;
    int v = (i < N_NODES) ? cnt[i] : 0;
    tmp[threadIdx.x] = v;
    __syncthreads();
    for (int off = 1; off < 256; off <<= 1) {
        int t = (threadIdx.x >= off) ? tmp[threadIdx.x - off] : 0;
        __syncthreads();
        tmp[threadIdx.x] += t;
        __syncthreads();
    }
    if (i < N_NODES) rp[i] = tmp[threadIdx.x] - v;   // local exclusive
    if (threadIdx.x == 255) sums[blockIdx.x] = tmp[255];
}

// single block: exclusive scan of the 391 block sums, in place
__global__ __launch_bounds__(512) void k_scan2(int* __restrict__ sums) {
    __shared__ int tmp[512];
    int i = threadIdx.x;
    int v = (i < NODE_BLKS) ? sums[i] : 0;
    tmp[i] = v;
    __syncthreads();
    for (int off = 1; off < 512; off <<= 1) {
        int t = (i >= off) ? tmp[i - off] : 0;
        __syncthreads();
        tmp[i] += t;
        __syncthreads();
    }
    if (i < NODE_BLKS) sums[i] = tmp[i] - v;   // exclusive
}

// rp += block offset; nxt = rp copy for fill; dinv = rsqrt(1+deg)
__global__ void k_finish(const int* __restrict__ cnt, int* __restrict__ rp,
                         const int* __restrict__ sums, int* __restrict__ nxt,
                         float* __restrict__ dinv) {
    int i = blockIdx.x * 256 + threadIdx.x;
    if (i < N_NODES) {
        int r = rp[i] + sums[i >> 8];
        rp[i] = r;
        nxt[i] = r;
        dinv[i] = rsqrtf(1.0f + (float)cnt[i]);
    }
    if (i == 0) rp[N_NODES] = N_EDGES;
}

__global__ void k_fill(const int* __restrict__ erow, const int* __restrict__ ecol,
                       int* __restrict__ nxt, int* __restrict__ eidx) {
    int e = blockIdx.x * 256 + threadIdx.x;
    if (e < N_EDGES) {
        int c = ecol[e];
        int pos = atomicAdd(&nxt[c], 1);
        eidx[pos] = erow[e];
    }
}

// ---------------- layer 0 GEMM: y = dinv[row] * (x @ W0) ----------------
__global__ __launch_bounds__(256) void k_gemm1(
    const float* __restrict__ x, const float* __restrict__ W0,
    const float* __restrict__ dinv, float* __restrict__ y) {
    __shared__ float Ws[N_FEAT][HIDDEN];
    __shared__ float Xs[4][N_FEAT];
    int tid = threadIdx.x;
    for (int i = tid; i < N_FEAT * HIDDEN; i += 256)
        Ws[i / HIDDEN][i % HIDDEN] = W0[i];
    int row0 = blockIdx.x * 4;
    for (int i = tid; i < 4 * N_FEAT; i += 256) {
        int r = i / N_FEAT, k = i - r * N_FEAT;
        int row = row0 + r;
        Xs[r][k] = (row < N_NODES) ? x[row * N_FEAT + k] : 0.0f;
    }
    __syncthreads();
    int r = tid >> 6, c = tid & 63;
    int row = row0 + r;
    if (row < N_NODES) {
        float acc = 0.0f;
        #pragma unroll
        for (int k = 0; k < N_FEAT; ++k) acc += Xs[r][k] * Ws[k][c];
        y[row * HIDDEN + c] = dinv[row] * acc;
    }
}

// ---------------- layer 0 aggregate: h[n] = dinv[n]*(y[n] + sum y[src]) + b0
// one 64-lane wave per node, lane = feature
__global__ __launch_bounds__(256) void k_agg0(
    const int* __restrict__ rp, const int* __restrict__ eidx,
    const float* __restrict__ dinv, const float* __restrict__ y,
    const float* __restrict__ b0, float* __restrict__ h) {
    int n = (blockIdx.x * 256 + threadIdx.x) >> 6;
    int lane = threadIdx.x & 63;
    if (n >= N_NODES) return;
    int beg = rp[n], end = rp[n + 1];
    float acc = y[n * HIDDEN + lane];   // self loop
    for (int e = beg; e < end; ++e) {
        int s = eidx[e];
        acc += y[s * HIDDEN + lane];
    }
    h[n * HIDDEN + lane] = dinv[n] * acc + b0[lane];
}

// ---------------- layer 1 GEMM: z = dinv[row] * (relu(h) @ W1) ----------
__global__ __launch_bounds__(256) void k_gemm2(
    const float* __restrict__ h, const float* __restrict__ W1,
    const float* __restrict__ dinv, float* __restrict__ z) {
    __shared__ float Ws[HIDDEN][48];
    __shared__ float Hs[4][HIDDEN];
    int tid = threadIdx.x;
    for (int i = tid; i < HIDDEN * N_CLASSES; i += 256) {
        int k = i / N_CLASSES, c = i - k * N_CLASSES;
        Ws[k][c] = W1[i];
    }
    int row0 = blockIdx.x * 4;
    for (int i = tid; i < 4 * HIDDEN; i += 256) {
        int r = i >> 6, k = i & 63;
        int row = row0 + r;
        Hs[r][k] = (row < N_NODES) ? fmaxf(h[row * HIDDEN + k], 0.0f) : 0.0f;
    }
    __syncthreads();
    int r = tid >> 6, c = tid & 63;
    int row = row0 + r;
    if (row < N_NODES && c < N_CLASSES) {
        float acc = 0.0f;
        #pragma unroll
        for (int k = 0; k < HIDDEN; ++k) acc += Hs[r][k] * Ws[k][c];
        z[row * N_CLASSES + c] = dinv[row] * acc;
    }
}

// ---------------- layer 1 aggregate: out[n] = dinv[n]*(z[n]+sum z[src]) + b1
__global__ __launch_bounds__(256) void k_agg1(
    const int* __restrict__ rp, const int* __restrict__ eidx,
    const float* __restrict__ dinv, const float* __restrict__ z,
    const float* __restrict__ b1, float* __restrict__ out) {
    int n = (blockIdx.x * 256 + threadIdx.x) >> 6;
    int lane = threadIdx.x & 63;
    if (n >= N_NODES) return;
    int beg = rp[n], end = rp[n + 1];
    float acc = (lane < N_CLASSES) ? z[n * N_CLASSES + lane] : 0.0f;
    for (int e = beg; e < end; ++e) {
        int s = eidx[e];
        if (lane < N_CLASSES) acc += z[s * N_CLASSES + lane];
    }
    if (lane < N_CLASSES)
        out[n * N_CLASSES + lane] = dinv[n] * acc + b1[lane];
}

extern "C" void kernel_launch(void* const* d_in, const int* in_sizes, int n_in,
                              void* d_out, int out_size, void* d_ws, size_t ws_size,
                              hipStream_t stream) {
    const float* x  = (const float*)d_in[0];
    const int*   ei = (const int*)d_in[1];
    const float* W0 = (const float*)d_in[2];
    const float* b0 = (const float*)d_in[3];
    const float* W1 = (const float*)d_in[4];
    const float* b1 = (const float*)d_in[5];
    float* out = (float*)d_out;

    char* ws = (char*)d_ws;
    float* dinv = (float*)(ws);                     // 400 KB
    int*   rp   = (int*)(ws + 400 * 1024);          // 400 KB + 4
    int*   nxt  = (int*)(ws + 800 * 1024);          // 400 KB
    int*   cnt  = (int*)(ws + 1200 * 1024);         // 400 KB
    int*   sums = (int*)(ws + 1640 * 1024);         // ~1.6 KB
    int*   eidx = (int*)(ws + 1644 * 1024);         // 6.4 MB
    float* y    = (float*)(ws + 8ull * 1024 * 1024);   // 25.6 MB
    float* h    = (float*)(ws + 34ull * 1024 * 1024);  // 25.6 MB  (ends ~59.6 MB)
    float* z    = y;                                   // reuse after agg0

    const int* erow = ei;             // edge_index[0] (sources)
    const int* ecol = ei + N_EDGES;   // edge_index[1] (destinations)

    // CSR build (counting sort by destination)
    k_zero  <<<NODE_BLKS, 256, 0, stream>>>(cnt);
    k_count <<<EDGE_BLKS, 256, 0, stream>>>(ecol, cnt);
    k_scan1 <<<NODE_BLKS, 256, 0, stream>>>(cnt, rp, sums);
    k_scan2 <<<1, 512, 0, stream>>>(sums);
    k_finish<<<NODE_BLKS, 256, 0, stream>>>(cnt, rp, sums, nxt, dinv);
    k_fill  <<<EDGE_BLKS, 256, 0, stream>>>(erow, ecol, nxt, eidx);

    // layer 0
    k_gemm1<<<(N_NODES + 3) / 4, 256, 0, stream>>>(x, W0, dinv, y);
    k_agg0 <<<(N_NODES * 64 + 255) / 256, 256, 0, stream>>>(rp, eidx, dinv, y, b0, h);

    // layer 1
    k_gemm2<<<(N_NODES + 3) / 4, 256, 0, stream>>>(h, W1, dinv, z);
    k_agg1 <<<(N_NODES * 64 + 255) / 256, 256, 0, stream>>>(rp, eidx, dinv, z, b1, out);
}

// Round 3
// 389.223 us; speedup vs baseline: 2.3397x; 1.6639x over previous
//
#include <hip/hip_runtime.h>
#include <hip/hip_fp16.h>

#define N_NODES   100000
#define N_EDGES   1600000
#define N_FEAT    100
#define HIDDEN    64
#define N_CLASSES 47
#define ZPAD      48
#define NODE_BLKS ((N_NODES + 255) / 256)   // 391
#define EDGE_BLKS ((N_EDGES + 255) / 256)   // 6250

// ---------------- CSR build: counting sort by destination ----------------

__global__ void k_zero(int* __restrict__ cnt) {
    int i = blockIdx.x * 256 + threadIdx.x;
    if (i < N_NODES) cnt[i] = 0;
}

__global__ void k_count(const int* __restrict__ ecol, int* __restrict__ cnt) {
    int e = blockIdx.x * 256 + threadIdx.x;
    if (e < N_EDGES) atomicAdd(&cnt[ecol[e]], 1);
}

__global__ __launch_bounds__(256) void k_scan1(const int* __restrict__ cnt,
                                               int* __restrict__ rp,
                                               int* __restrict__ sums) {
    __shared__ int tmp[256];
    int i = blockIdx.x * 256 + threadIdx.x;
    int v = (i < N_NODES) ? cnt[i] : 0;
    tmp[threadIdx.x] = v;
    __syncthreads();
    for (int off = 1; off < 256; off <<= 1) {
        int t = (threadIdx.x >= off) ? tmp[threadIdx.x - off] : 0;
        __syncthreads();
        tmp[threadIdx.x] += t;
        __syncthreads();
    }
    if (i < N_NODES) rp[i] = tmp[threadIdx.x] - v;
    if (threadIdx.x == 255) sums[blockIdx.x] = tmp[255];
}

__global__ __launch_bounds__(512) void k_scan2(int* __restrict__ sums) {
    __shared__ int tmp[512];
    int i = threadIdx.x;
    int v = (i < NODE_BLKS) ? sums[i] : 0;
    tmp[i] = v;
    __syncthreads();
    for (int off = 1; off < 512; off <<= 1) {
        int t = (i >= off) ? tmp[i - off] : 0;
        __syncthreads();
        tmp[i] += t;
        __syncthreads();
    }
    if (i < NODE_BLKS) sums[i] = tmp[i] - v;
}

__global__ void k_finish(const int* __restrict__ cnt, int* __restrict__ rp,
                         const int* __restrict__ sums, int* __restrict__ nxt,
                         float* __restrict__ dinv) {
    int i = blockIdx.x * 256 + threadIdx.x;
    if (i < N_NODES) {
        int r = rp[i] + sums[i >> 8];
        rp[i] = r;
        nxt[i] = r;
        dinv[i] = rsqrtf(1.0f + (float)cnt[i]);
    }
    if (i == 0) rp[N_NODES] = N_EDGES;
}

__global__ void k_fill(const int* __restrict__ erow, const int* __restrict__ ecol,
                       int* __restrict__ nxt, int* __restrict__ eidx) {
    int e = blockIdx.x * 256 + threadIdx.x;
    if (e < N_EDGES) {
        int c = ecol[e];
        int pos = atomicAdd(&nxt[c], 1);
        eidx[pos] = erow[e];
    }
}

// -------- layer 0 GEMM: yh = fp16( dinv[row] * (x @ W0) ), 16 rows/block ----
__global__ __launch_bounds__(256) void k_gemm1(
    const float* __restrict__ x, const float* __restrict__ W0,
    const float* __restrict__ dinv, __half* __restrict__ yh) {
    __shared__ float Ws[N_FEAT][HIDDEN];   // 25600 B
    __shared__ float Xs[16][N_FEAT];       // 6400 B
    int tid = threadIdx.x;
    for (int i = tid; i < N_FEAT * HIDDEN; i += 256)
        Ws[i / HIDDEN][i % HIDDEN] = W0[i];
    int row0 = blockIdx.x * 16;
    for (int i = tid; i < 16 * N_FEAT; i += 256) {
        int r = i / N_FEAT, k = i - r * N_FEAT;
        int row = row0 + r;
        Xs[r][k] = (row < N_NODES) ? x[row * N_FEAT + k] : 0.0f;
    }
    __syncthreads();
    int c = tid & 63;
    int rb = (tid >> 6) * 4;
    float a0 = 0, a1 = 0, a2 = 0, a3 = 0;
    #pragma unroll 4
    for (int k = 0; k < N_FEAT; ++k) {
        float w = Ws[k][c];
        a0 += Xs[rb + 0][k] * w;
        a1 += Xs[rb + 1][k] * w;
        a2 += Xs[rb + 2][k] * w;
        a3 += Xs[rb + 3][k] * w;
    }
    int row = row0 + rb;
    if (row + 0 < N_NODES) yh[(row + 0) * HIDDEN + c] = __float2half(dinv[row + 0] * a0);
    if (row + 1 < N_NODES) yh[(row + 1) * HIDDEN + c] = __float2half(dinv[row + 1] * a1);
    if (row + 2 < N_NODES) yh[(row + 2) * HIDDEN + c] = __float2half(dinv[row + 2] * a2);
    if (row + 3 < N_NODES) yh[(row + 3) * HIDDEN + c] = __float2half(dinv[row + 3] * a3);
}

// -------- layer 0 aggregate: h[n] = dinv[n]*(yh[n] + sum yh[src]) + b0 ------
// one wave per node; edge list preloaded into registers, 8-deep gather pipe
__global__ __launch_bounds__(256) void k_agg0(
    const int* __restrict__ rp, const int* __restrict__ eidx,
    const float* __restrict__ dinv, const __half* __restrict__ yh,
    const float* __restrict__ b0, float* __restrict__ h) {
    int n = (blockIdx.x * 256 + threadIdx.x) >> 6;
    int lane = threadIdx.x & 63;
    if (n >= N_NODES) return;
    int beg = rp[n], end = rp[n + 1];
    int deg = end - beg;
    int idx = beg + lane;
    int se = (idx < end) ? eidx[idx] : 0;   // coalesced edge-list preload
    float acc = __half2float(yh[n * HIDDEN + lane]);   // self loop
    int m = deg < 64 ? deg : 64;
    int j = 0;
    for (; j + 8 <= m; j += 8) {
        int s0 = __shfl(se, j + 0), s1 = __shfl(se, j + 1);
        int s2 = __shfl(se, j + 2), s3 = __shfl(se, j + 3);
        int s4 = __shfl(se, j + 4), s5 = __shfl(se, j + 5);
        int s6 = __shfl(se, j + 6), s7 = __shfl(se, j + 7);
        float v0 = __half2float(yh[s0 * HIDDEN + lane]);
        float v1 = __half2float(yh[s1 * HIDDEN + lane]);
        float v2 = __half2float(yh[s2 * HIDDEN + lane]);
        float v3 = __half2float(yh[s3 * HIDDEN + lane]);
        float v4 = __half2float(yh[s4 * HIDDEN + lane]);
        float v5 = __half2float(yh[s5 * HIDDEN + lane]);
        float v6 = __half2float(yh[s6 * HIDDEN + lane]);
        float v7 = __half2float(yh[s7 * HIDDEN + lane]);
        acc += ((v0 + v1) + (v2 + v3)) + ((v4 + v5) + (v6 + v7));
    }
    for (; j < m; ++j) {
        int s = __shfl(se, j);
        acc += __half2float(yh[s * HIDDEN + lane]);
    }
    if (deg > 64) {
        for (int e = beg + 64; e < end; ++e)
            acc += __half2float(yh[eidx[e] * HIDDEN + lane]);
    }
    h[n * HIDDEN + lane] = dinv[n] * acc + b0[lane];
}

// -------- layer 1 GEMM: zh = fp16( dinv[row] * (relu(h) @ W1) ), pad 48 -----
__global__ __launch_bounds__(256) void k_gemm2(
    const float* __restrict__ h, const float* __restrict__ W1,
    const float* __restrict__ dinv, __half* __restrict__ zh) {
    __shared__ float Ws[HIDDEN][ZPAD];   // 12288 B
    __shared__ float Hs[16][HIDDEN];     // 4096 B
    int tid = threadIdx.x;
    for (int i = tid; i < HIDDEN * N_CLASSES; i += 256) {
        int k = i / N_CLASSES, c = i - k * N_CLASSES;
        Ws[k][c] = W1[i];
    }
    int row0 = blockIdx.x * 16;
    for (int i = tid; i < 16 * HIDDEN; i += 256) {
        int r = i >> 6, k = i & 63;
        int row = row0 + r;
        Hs[r][k] = (row < N_NODES) ? fmaxf(h[row * HIDDEN + k], 0.0f) : 0.0f;
    }
    __syncthreads();
    int c = tid & 63;
    int rb = (tid >> 6) * 4;
    if (c < ZPAD) {
        float a0 = 0, a1 = 0, a2 = 0, a3 = 0;
        if (c < N_CLASSES) {
            #pragma unroll 4
            for (int k = 0; k < HIDDEN; ++k) {
                float w = Ws[k][c];
                a0 += Hs[rb + 0][k] * w;
                a1 += Hs[rb + 1][k] * w;
                a2 += Hs[rb + 2][k] * w;
                a3 += Hs[rb + 3][k] * w;
            }
        }
        int row = row0 + rb;
        if (row + 0 < N_NODES) zh[(row + 0) * ZPAD + c] = __float2half((c < N_CLASSES) ? dinv[row + 0] * a0 : 0.0f);
        if (row + 1 < N_NODES) zh[(row + 1) * ZPAD + c] = __float2half((c < N_CLASSES) ? dinv[row + 1] * a1 : 0.0f);
        if (row + 2 < N_NODES) zh[(row + 2) * ZPAD + c] = __float2half((c < N_CLASSES) ? dinv[row + 2] * a2 : 0.0f);
        if (row + 3 < N_NODES) zh[(row + 3) * ZPAD + c] = __float2half((c < N_CLASSES) ? dinv[row + 3] * a3 : 0.0f);
    }
}

// -------- layer 1 aggregate: out[n] = dinv[n]*(zh[n]+sum zh[src]) + b1 ------
__global__ __launch_bounds__(256) void k_agg1(
    const int* __restrict__ rp, const int* __restrict__ eidx,
    const float* __restrict__ dinv, const __half* __restrict__ zh,
    const float* __restrict__ b1, float* __restrict__ out) {
    int n = (blockIdx.x * 256 + threadIdx.x) >> 6;
    int lane = threadIdx.x & 63;
    if (n >= N_NODES) return;
    int beg = rp[n], end = rp[n + 1];
    int deg = end - beg;
    int idx = beg + lane;
    int se = (idx < end) ? eidx[idx] : 0;
    float acc = (lane < ZPAD) ? __half2float(zh[n * ZPAD + lane]) : 0.0f;
    int m = deg < 64 ? deg : 64;
    int j = 0;
    for (; j + 8 <= m; j += 8) {
        int s0 = __shfl(se, j + 0), s1 = __shfl(se, j + 1);
        int s2 = __shfl(se, j + 2), s3 = __shfl(se, j + 3);
        int s4 = __shfl(se, j + 4), s5 = __shfl(se, j + 5);
        int s6 = __shfl(se, j + 6), s7 = __shfl(se, j + 7);
        if (lane < ZPAD) {
            float v0 = __half2float(zh[s0 * ZPAD + lane]);
            float v1 = __half2float(zh[s1 * ZPAD + lane]);
            float v2 = __half2float(zh[s2 * ZPAD + lane]);
            float v3 = __half2float(zh[s3 * ZPAD + lane]);
            float v4 = __half2float(zh[s4 * ZPAD + lane]);
            float v5 = __half2float(zh[s5 * ZPAD + lane]);
            float v6 = __half2float(zh[s6 * ZPAD + lane]);
            float v7 = __half2float(zh[s7 * ZPAD + lane]);
            acc += ((v0 + v1) + (v2 + v3)) + ((v4 + v5) + (v6 + v7));
        }
    }
    for (; j < m; ++j) {
        int s = __shfl(se, j);
        if (lane < ZPAD) acc += __half2float(zh[s * ZPAD + lane]);
    }
    if (deg > 64) {
        for (int e = beg + 64; e < end; ++e) {
            int s = eidx[e];
            if (lane < ZPAD) acc += __half2float(zh[s * ZPAD + lane]);
        }
    }
    if (lane < N_CLASSES)
        out[n * N_CLASSES + lane] = dinv[n] * acc + b1[lane];
}

extern "C" void kernel_launch(void* const* d_in, const int* in_sizes, int n_in,
                              void* d_out, int out_size, void* d_ws, size_t ws_size,
                              hipStream_t stream) {
    const float* x  = (const float*)d_in[0];
    const int*   ei = (const int*)d_in[1];
    const float* W0 = (const float*)d_in[2];
    const float* b0 = (const float*)d_in[3];
    const float* W1 = (const float*)d_in[4];
    const float* b1 = (const float*)d_in[5];
    float* out = (float*)d_out;

    char* ws = (char*)d_ws;
    float*  dinv = (float*)(ws);                        // 400 KB
    int*    rp   = (int*)(ws + 412 * 1024);             // 400 KB + 4
    int*    nxt  = (int*)(ws + 824 * 1024);             // 400 KB
    int*    cnt  = (int*)(ws + 1236 * 1024);            // 400 KB
    int*    sums = (int*)(ws + 1648 * 1024);            // 2 KB
    int*    eidx = (int*)(ws + 1664 * 1024);            // 6.4 MB -> ends ~8.1 MB
    __half* yh   = (__half*)(ws + 9ull * 1024 * 1024);  // 12.8 MB -> ends ~21.8 MB
    float*  h    = (float*)(ws + 24ull * 1024 * 1024);  // 25.6 MB -> ends ~49.6 MB
    __half* zh   = yh;                                  // reuse after agg0 (9.6 MB)

    const int* erow = ei;             // edge_index[0] (sources)
    const int* ecol = ei + N_EDGES;   // edge_index[1] (destinations)

    k_zero  <<<NODE_BLKS, 256, 0, stream>>>(cnt);
    k_count <<<EDGE_BLKS, 256, 0, stream>>>(ecol, cnt);
    k_scan1 <<<NODE_BLKS, 256, 0, stream>>>(cnt, rp, sums);
    k_scan2 <<<1, 512, 0, stream>>>(sums);
    k_finish<<<NODE_BLKS, 256, 0, stream>>>(cnt, rp, sums, nxt, dinv);
    k_fill  <<<EDGE_BLKS, 256, 0, stream>>>(erow, ecol, nxt, eidx);

    k_gemm1<<<(N_NODES + 15) / 16, 256, 0, stream>>>(x, W0, dinv, yh);
    k_agg0 <<<(N_NODES * 64 + 255) / 256, 256, 0, stream>>>(rp, eidx, dinv, yh, b0, h);

    k_gemm2<<<(N_NODES + 15) / 16, 256, 0, stream>>>(h, W1, dinv, zh);
    k_agg1 <<<(N_NODES * 64 + 255) / 256, 256, 0, stream>>>(rp, eidx, dinv, zh, b1, out);
}